// Round 11
// baseline (616.758 us; speedup 1.0000x reference)
//
#include <hip/hip_runtime.h>

// Problem constants (from reference)
#define B_      128
#define NPIX    32      // N = M = 32
#define NNEO    30      // N-2
#define CPAD    20      // padded channel stride (16B-aligned pixel blocks)
#define OUTD    21      // OUT_DIM
#define ITERS   10
#define THRESHV 0.0007f
#define HSTRIDE 31      // s_h cell stride: gcd(31,32)=1 -> conflict-free

#define NCELLS      (B_ * NNEO * NNEO)   // 115,200
#define CLASS_ELEMS (NCELLS * 3)         // 345,600
#define HALOROW     (NPIX * CPAD)        // 640 floats per pixel row (interleaved)

// ---------------------------------------------------------------------------
// R21: PERSISTENT + R14's half-split compute (the measured-best 33.6us/step
// structure) at 2 blocks/CU.
// R20 post-mortem: 1-thread-per-cell persistence caps TLP at NCELLS/256CU =
// 1.76 waves/SIMD (occupancy 22.8%) -> s_load weight stream unhideable ->
// 38.5us/step. Fix: half-split (wave-uniform h -> s_load broadcast kept),
// 4 blocks/image (rows {8,8,7,7}), grid 512 x 512 thr = EXACTLY 2 blocks/CU,
// all resident, 16 waves/CU (2x R20).
//  - State tile (nr+2 rows, interleaved CPAD) lives in LDS all 10 steps.
//  - 2-partner chain halo: block publishes pixel row r0+1 (to prev) and
//    r0+nr (to next) into double-buffered global slots; per-block monotone
//    flag, agent-scope release/acquire (R20-proven scheme).
//  - perc: h1 computes movement, writes s_perc (LDS); both halves read next
//    step. No global perc traffic.
//  - Removes vs R14: per-step staging, init kernel, 10 launch drains, perc IO.
// Numerics: accumulation order identical to R14 (bias; patches (pr,pc) asc:
// img row, ch rows 0..18; posx; posy; L2/L3 k ascending with reg/LDS splice).
// ---------------------------------------------------------------------------

#define ROW15(A, x, wrp) do { const float xx_ = (x); \
    const float* __restrict__ w_ = (wrp); \
    _Pragma("unroll") for (int o_ = 0; o_ < 15; o_++) (A)[o_] += xx_ * w_[o_]; \
} while (0)

#define ROW12(A, x, wrp) do { const float xx_ = (x); \
    const float* __restrict__ w_ = (wrp); \
    _Pragma("unroll") for (int o_ = 0; o_ < 12; o_++) (A)[o_] += xx_ * w_[o_]; \
} while (0)

#define ROW9(A, x, wrp) do { const float xx_ = (x); \
    const float* __restrict__ w_ = (wrp); \
    _Pragma("unroll") for (int o_ = 0; o_ < 9; o_++) (A)[o_] += xx_ * w_[o_]; \
} while (0)

__global__ void nca_zero_flags(int* __restrict__ flags) {
    if (threadIdx.x < 512) flags[threadIdx.x] = 0;
}

__global__ __launch_bounds__(512, 4)
void nca_persist(const float* __restrict__ img,
                 const float* __restrict__ W1, const float* __restrict__ b1,
                 const float* __restrict__ W2, const float* __restrict__ b2,
                 const float* __restrict__ W3, const float* __restrict__ b3,
                 float* __restrict__ hbuf, int* __restrict__ flags,
                 float* __restrict__ guesses_out, float* __restrict__ class_out)
{
    __shared__ float s_state[10 * HALOROW];   // 25.6 KB (nr+2 <= 10 rows)
    __shared__ float s_img[NPIX * NPIX];      // 4 KB
    __shared__ float s_h[256 * HSTRIDE];      // 31.7 KB
    __shared__ int   s_perc[256][2];          // 2 KB      (total 63.3 KB)

    const int bid = blockIdx.x;
    const int b   = bid >> 2;                 // image
    const int q   = bid & 3;                  // band: rows {8,8,7,7}
    const int r0  = (q < 2) ? q * 8 : 16 + (q - 2) * 7;
    const int nr  = (q < 2) ? 8 : 7;
    const int tid = threadIdx.x;
    const int h   = __builtin_amdgcn_readfirstlane(tid >> 8);  // wave-uniform
    const int cell = tid & 255;
    const int qoff = h * 15;

    // init: zero whole tile (borders + halos), load image
    for (int t2 = tid; t2 < 10 * HALOROW; t2 += 512) s_state[t2] = 0.0f;
    if (tid < 256)
        ((float4*)s_img)[tid] =
            ((const float4*)(img + (size_t)b * (NPIX * NPIX)))[tid];

    const int cells = nr * NNEO;
    const bool active = cell < cells;
    int r = 0, j = 0;
    if (active) { r = cell / NNEO; j = cell - r * NNEO; }
    const int i = r0 + r;                     // global cell row
    const int gcell = (b * NNEO + i) * NNEO + j;
    int px = i, py = j;

    // halo slots: per block 2 dirs x 2 bufs x HALOROW
    float* __restrict__ myslot = hbuf + (size_t)bid * (4 * HALOROW);
    const float* __restrict__ prevslot =
        (q > 0) ? hbuf + (size_t)(bid - 1) * (4 * HALOROW) + 2 * HALOROW : nullptr;
    const float* __restrict__ nextslot =
        (q < 3) ? hbuf + (size_t)(bid + 1) * (4 * HALOROW) : nullptr;
    int* pflag = (q > 0) ? flags + (bid - 1) : nullptr;
    int* nflag = (q < 3) ? flags + (bid + 1) : nullptr;

    __syncthreads();

    for (int t = 0; t < ITERS; t++) {
        // ---- receive halos (rows updated at t-1) --------------------------
        if (t > 0) {
            if (tid == 0) {
                if (pflag)
                    while (__hip_atomic_load(pflag, __ATOMIC_ACQUIRE,
                                             __HIP_MEMORY_SCOPE_AGENT) < t)
                        __builtin_amdgcn_s_sleep(16);
                if (nflag)
                    while (__hip_atomic_load(nflag, __ATOMIC_ACQUIRE,
                                             __HIP_MEMORY_SCOPE_AGENT) < t)
                        __builtin_amdgcn_s_sleep(16);
            }
            __syncthreads();
            const int buf = (t - 1) & 1;
            if (q > 0)
                for (int t2 = tid; t2 < HALOROW; t2 += 512)
                    s_state[t2] = prevslot[buf * HALOROW + t2];       // row 0
            if (q < 3)
                for (int t2 = tid; t2 < HALOROW; t2 += 512)
                    s_state[(nr + 1) * HALOROW + t2] =
                        nextslot[buf * HALOROW + t2];                 // row nr+1
            __syncthreads();
            if (active) { px = s_perc[cell][0]; py = s_perc[cell][1]; }
        }

        // ---------------- layer 1: 182 -> 30 (15 @ qoff) -------------------
        float a1[15];
        {
            float acc[15];
#pragma unroll
            for (int o = 0; o < 15; o++) acc[o] = b1[qoff + o];
            if (active) {
                if (t == 0) {
#pragma clang loop unroll(disable)
                    for (int pr = 0; pr < 3; pr++) {
#pragma clang loop unroll(disable)
                        for (int pc = 0; pc < 3; pc++) {
                            const float iv = s_img[(px + pr) * NPIX + (py + pc)];
                            ROW15(acc, iv, W1 + (pr * 3 + pc) * 600 + qoff);
                        }
                    }
                } else {
#pragma clang loop unroll(disable)
                    for (int pr = 0; pr < 3; pr++) {
#pragma clang loop unroll(disable)
                        for (int pc = 0; pc < 3; pc++) {
                            const float iv = s_img[(px + pr) * NPIX + (py + pc)];
                            const float* __restrict__ wp =
                                W1 + (pr * 3 + pc) * 600 + qoff;
                            const float4* __restrict__ sp = (const float4*)
                                &s_state[((r + pr) * NPIX + (j + pc)) * CPAD];
                            const float4 ga = sp[0], gb = sp[1], gc = sp[2],
                                         gd = sp[3], ge = sp[4];
                            ROW15(acc, iv,   wp);
                            ROW15(acc, ga.x, wp + 30);  ROW15(acc, ga.y, wp + 60);
                            ROW15(acc, ga.z, wp + 90);  ROW15(acc, ga.w, wp + 120);
                            ROW15(acc, gb.x, wp + 150); ROW15(acc, gb.y, wp + 180);
                            ROW15(acc, gb.z, wp + 210); ROW15(acc, gb.w, wp + 240);
                            ROW15(acc, gc.x, wp + 270); ROW15(acc, gc.y, wp + 300);
                            ROW15(acc, gc.z, wp + 330); ROW15(acc, gc.w, wp + 360);
                            ROW15(acc, gd.x, wp + 390); ROW15(acc, gd.y, wp + 420);
                            ROW15(acc, gd.z, wp + 450); ROW15(acc, gd.w, wp + 480);
                            ROW15(acc, ge.x, wp + 510); ROW15(acc, ge.y, wp + 540);
                            ROW15(acc, ge.z, wp + 570);
                        }
                    }
                }
                const float posx = (float)(px - 16) * 0.0625f;
                const float posy = (float)(py - 16) * 0.0625f;
                ROW15(acc, posx, W1 + 180 * 30 + qoff);
                ROW15(acc, posy, W1 + 181 * 30 + qoff);
            }
#pragma unroll
            for (int o = 0; o < 15; o++) a1[o] = fmaxf(acc[o], 0.0f);
            if (active) {
#pragma unroll
                for (int o = 0; o < 15; o++)
                    s_h[cell * HSTRIDE + qoff + o] = a1[o];
            }
        }
        __syncthreads();                      // B2: a1 visible

        // ---------------- layer 2: 30 -> 30 (15 @ qoff) --------------------
        float h2[15];
        {
            float acc[15];
#pragma unroll
            for (int o = 0; o < 15; o++) acc[o] = b2[qoff + o];
            if (active) {
                if (h == 0) {
#pragma unroll
                    for (int k = 0; k < 15; k++)
                        ROW15(acc, a1[k], W2 + k * 30);
#pragma clang loop unroll(disable)
                    for (int k = 15; k < 30; k++) {
                        const float x = s_h[cell * HSTRIDE + k];
                        ROW15(acc, x, W2 + k * 30);
                    }
                } else {
#pragma clang loop unroll(disable)
                    for (int k = 0; k < 15; k++) {
                        const float x = s_h[cell * HSTRIDE + k];
                        ROW15(acc, x, W2 + k * 30 + 15);
                    }
#pragma unroll
                    for (int k = 0; k < 15; k++)
                        ROW15(acc, a1[k], W2 + (k + 15) * 30 + 15);
                }
            }
#pragma unroll
            for (int o = 0; o < 15; o++) h2[o] = fmaxf(acc[o], 0.0f);
        }
        __syncthreads();                      // B3: all a1 reads done
        if (active) {
#pragma unroll
            for (int o = 0; o < 15; o++)
                s_h[cell * HSTRIDE + qoff + o] = h2[o];
        }
        __syncthreads();                      // B4: h2 visible

        // ---------------- layer 3 + update/outputs -------------------------
        if (active) {
            const int lc = ((r + 1) * NPIX + (j + 1)) * CPAD;
            if (h == 0) {
                float ov[12];
#pragma unroll
                for (int c = 0; c < 12; c++) ov[c] = b3[c];
#pragma unroll
                for (int k = 0; k < 15; k++)
                    ROW12(ov, h2[k], W3 + k * 21);
#pragma clang loop unroll(disable)
                for (int k = 15; k < 30; k++) {
                    const float x = s_h[cell * HSTRIDE + k];
                    ROW12(ov, x, W3 + k * 21);
                }
                if (t == ITERS - 1) {
                    float* __restrict__ g = guesses_out + (size_t)gcell * OUTD;
#pragma unroll
                    for (int c = 0; c < 12; c++) g[c] = ov[c];
                } else {
#pragma unroll
                    for (int c = 0; c < 12; c++) s_state[lc + c] += ov[c];
                }
            } else {
                float ov[9];                  // global cols 12..20
#pragma unroll
                for (int c = 0; c < 9; c++) ov[c] = b3[12 + c];
#pragma clang loop unroll(disable)
                for (int k = 0; k < 15; k++) {
                    const float x = s_h[cell * HSTRIDE + k];
                    ROW9(ov, x, W3 + k * 21 + 12);
                }
#pragma unroll
                for (int k = 0; k < 15; k++)
                    ROW9(ov, h2[k], W3 + (k + 15) * 21 + 12);
                if (t == ITERS - 1) {
                    float* __restrict__ g = guesses_out + (size_t)gcell * OUTD;
#pragma unroll
                    for (int c = 0; c < 9; c++) g[12 + c] = ov[c];
                    float* __restrict__ cs = class_out + (size_t)gcell * 3;
#pragma unroll
                    for (int cc = 0; cc < 3; cc++)
                        cs[cc] = s_state[lc + 16 + cc] + ov[4 + cc];
                } else {
#pragma unroll
                    for (int c = 0; c < 7; c++)
                        s_state[lc + 12 + c] += ov[c];
                    int dxm = (ov[7] > THRESHV) ? 1 : ((ov[7] < -THRESHV) ? -1 : 0);
                    int dym = (ov[8] > THRESHV) ? 1 : ((ov[8] < -THRESHV) ? -1 : 0);
                    px += dxm; py += dym;
                    px = (px < 0) ? 0 : ((px > NNEO - 1) ? NNEO - 1 : px);
                    py = (py < 0) ? 0 : ((py > NNEO - 1) ? NNEO - 1 : py);
                    s_perc[cell][0] = px;
                    s_perc[cell][1] = py;
                }
            }
        }

        if (t < ITERS - 1) {
            __syncthreads();                  // updates + s_perc visible
            // ---- publish boundary rows (pixel r0+1 = LDS 1, r0+nr = LDS nr)
            const int buf = t & 1;
            for (int t2 = tid; t2 < HALOROW; t2 += 512) {
                myslot[buf * HALOROW + t2]               = s_state[HALOROW + t2];
                myslot[(2 + buf) * HALOROW + t2] = s_state[nr * HALOROW + t2];
            }
            __syncthreads();                  // vmcnt drain: stores in L2
            if (tid == 0)
                __hip_atomic_store(flags + bid, t + 1, __ATOMIC_RELEASE,
                                   __HIP_MEMORY_SCOPE_AGENT);
        }
    }
}

extern "C" void kernel_launch(void* const* d_in, const int* in_sizes, int n_in,
                              void* d_out, int out_size, void* d_ws, size_t ws_size,
                              hipStream_t stream) {
    const float* img = (const float*)d_in[0];
    const float* W1  = (const float*)d_in[1];
    const float* b1  = (const float*)d_in[2];
    const float* W2  = (const float*)d_in[3];
    const float* b2  = (const float*)d_in[4];
    const float* W3  = (const float*)d_in[5];
    const float* b3  = (const float*)d_in[6];

    float* out = (float*)d_out;
    float* class_out   = out;                 // 345,600 floats
    float* guesses_out = out + CLASS_ELEMS;   // 2,419,200 floats

    float* hbuf  = (float*)d_ws;              // 512 blocks x 4 x 640 floats
    int*   flags = (int*)(hbuf + 512 * 4 * HALOROW);

    nca_zero_flags<<<1, 512, 0, stream>>>(flags);

    nca_persist<<<512, 512, 0, stream>>>(img, W1, b1, W2, b2, W3, b3,
                                         hbuf, flags,
                                         guesses_out, class_out);
}

// Round 12
// 348.271 us; speedup vs baseline: 1.7709x; 1.7709x over previous
//
#include <hip/hip_runtime.h>

// Problem constants (from reference)
#define B_      128
#define NPIX    32      // N = M = 32
#define NNEO    30      // N-2
#define CPAD    20      // padded channel stride (16B-aligned pixel blocks)
#define OUTD    21      // OUT_DIM
#define ITERS   10
#define THRESHV 0.0007f
#define HSTRIDE 31      // s_h cell stride: gcd(31,32)=1 -> conflict-free

#define STATE_ELEMS_PAD (B_ * NPIX * NPIX * CPAD)  // 2,621,440 floats per buffer
#define NCELLS      (B_ * NNEO * NNEO)             // 115,200
#define CLASS_ELEMS (NCELLS * 3)                   // 345,600

// ---------------------------------------------------------------------------
// R22 = R14 (proven best, 336.4us) + two safe micro-opts. Persistence is
// abandoned: R20 (pair-halo) capped at 1.76 waves/SIMD; R21 (chain-halo)
// showed agent-scope release/acquire = per-XCD L2 writeback/invalidate per
// block per step -> +29us/step. R14's decomposition (VALU 12.7 + LDS 9 +
// staging 4 + barriers 4 + launch 2 ~= 33.6 measured) says: remove a
// component or stay put.
// This round removes part of the staging cost:
//  1. global_load_lds width=16 for the state staging (linear copy, wave-
//     uniform LDS base + lane*16 exactly matches s4[t]) — no VGPR round-trip
//     (guide Common-mistake #1). __has_builtin fallback keeps R14 path.
//  2. perc loads hoisted ABOVE the staging loop (latency hides under staging
//     issue instead of sitting exposed after barrier B1).
// Everything else (layout, splits, accumulation order) is R14 verbatim ->
// absmax must be exactly 0.0078125.
// MODE: 0 = first step (state==0, perc=identity), 1 = mid, 2 = last.
// ---------------------------------------------------------------------------

__global__ void nca_init(float* __restrict__ stateA, float* __restrict__ stateB) {
    int idx = blockIdx.x * blockDim.x + threadIdx.x;
    const int total = B_ * 124 * CPAD;
    if (idx >= total) return;
    int c  = idx % CPAD;
    int t2 = idx / CPAD;
    int cellp = t2 % 124;
    int b    = t2 / 124;
    int i, j;
    if (cellp < 32)      { i = 0;  j = cellp; }
    else if (cellp < 64) { i = 31; j = cellp - 32; }
    else { int k = cellp - 64; i = 1 + (k >> 1); j = (k & 1) ? 31 : 0; }
    size_t off = (((size_t)b * NPIX + i) * NPIX + j) * CPAD + c;
    stateA[off] = 0.0f;
    stateB[off] = 0.0f;
}

#define ROW15(A, x, wrp) do { const float xx_ = (x); \
    const float* __restrict__ w_ = (wrp); \
    _Pragma("unroll") for (int o_ = 0; o_ < 15; o_++) (A)[o_] += xx_ * w_[o_]; \
} while (0)

#define ROW12(A, x, wrp) do { const float xx_ = (x); \
    const float* __restrict__ w_ = (wrp); \
    _Pragma("unroll") for (int o_ = 0; o_ < 12; o_++) (A)[o_] += xx_ * w_[o_]; \
} while (0)

#define ROW9(A, x, wrp) do { const float xx_ = (x); \
    const float* __restrict__ w_ = (wrp); \
    _Pragma("unroll") for (int o_ = 0; o_ < 9; o_++) (A)[o_] += xx_ * w_[o_]; \
} while (0)

template<int MODE>
__global__ __launch_bounds__(512, 4)
void nca_step(const float* __restrict__ img,
              const float* __restrict__ W1, const float* __restrict__ b1,
              const float* __restrict__ W2, const float* __restrict__ b2,
              const float* __restrict__ W3, const float* __restrict__ b3,
              const float* __restrict__ state_old, float* __restrict__ state_new,
              int* perc, float* __restrict__ guesses_out,
              float* __restrict__ class_out)
{
    __shared__ float s_state[10 * NPIX * CPAD];   // 25.6 KB (nr+2 <= 10 rows)
    __shared__ float s_img[NPIX * NPIX];          // 4 KB
    __shared__ float s_h[256 * HSTRIDE];          // 31.7 KB   (total 61.3 KB)

    const int b   = blockIdx.y;
    const int rg  = blockIdx.x;                   // 4 groups: rows {8,8,8,6}
    const int i0  = rg * 8;
    const int nr  = (rg == 3) ? 6 : 8;
    const int tid = threadIdx.x;
    const int h   = __builtin_amdgcn_readfirstlane(tid >> 8);  // wave-uniform half
    const int cell = tid & 255;
    const int qoff = h * 15;

    // ---- cell geometry + perc prefetch (BEFORE staging: latency overlap) --
    const int cells = nr * NNEO;
    const bool active = cell < cells;
    int r = 0, j = 0, i = 0, gcell = 0, px = 0, py = 0;
    if (active) {
        r = cell / NNEO;
        j = cell - r * NNEO;
        i = i0 + r;
        gcell = (b * NNEO + i) * NNEO + j;
        if (MODE == 0) { px = i; py = j; }
        else           { px = perc[2 * gcell]; py = perc[2 * gcell + 1]; }
    }

    // ---- stage state rows [i0, i0+nr+2) and the image ----------------------
    if (MODE != 0) {
        const int n4 = (nr + 2) * (NPIX * CPAD / 4);   // 1600 or 1280 float4
        const float4* __restrict__ gstate4 =
            (const float4*)(state_old + ((size_t)b * NPIX + i0) * (NPIX * CPAD));
#if __has_builtin(__builtin_amdgcn_global_load_lds)
        // Direct global->LDS DMA, 16B/lane: dest = wave-uniform base + lane*16
        // which equals s4[t] exactly for t = (t - lane) + lane.
        const int lane = tid & 63;
        for (int t = tid; t < n4; t += 512) {
            const int tb = t - lane;                   // wave-uniform f4 index
            __builtin_amdgcn_global_load_lds(
                (const __attribute__((address_space(1))) void*)(gstate4 + t),
                (__attribute__((address_space(3))) void*)
                    ((float4*)s_state + tb),
                16, 0, 0);
        }
#else
        float4* s4 = (float4*)s_state;
        for (int t = tid; t < n4; t += 512) s4[t] = gstate4[t];
#endif
    }
    if (tid < 256)
        ((float4*)s_img)[tid] = ((const float4*)(img + (size_t)b * NPIX * NPIX))[tid];
    __syncthreads();                                  // B1 (drains vmcnt)

    // ---------------- layer 1: 182 -> 30 (this thread: 15 @ qoff) ----------
    float a1[15];
    {
        float acc[15];
#pragma unroll
        for (int o = 0; o < 15; o++) acc[o] = b1[qoff + o];
        if (active) {
            if (MODE == 0) {
#pragma clang loop unroll(disable)
                for (int pr = 0; pr < 3; pr++) {
#pragma clang loop unroll(disable)
                    for (int pc = 0; pc < 3; pc++) {
                        const float iv = s_img[(px + pr) * NPIX + (py + pc)];
                        ROW15(acc, iv, W1 + (pr * 3 + pc) * 600 + qoff);
                    }
                }
            } else {
#pragma clang loop unroll(disable)
                for (int pr = 0; pr < 3; pr++) {
#pragma clang loop unroll(disable)
                    for (int pc = 0; pc < 3; pc++) {
                        const float iv = s_img[(px + pr) * NPIX + (py + pc)];
                        const float* __restrict__ wp = W1 + (pr * 3 + pc) * 600 + qoff;
                        const float4* __restrict__ sp =
                            (const float4*)&s_state[((r + pr) * NPIX + (j + pc)) * CPAD];
                        const float4 ga = sp[0], gb = sp[1], gc = sp[2],
                                     gd = sp[3], ge = sp[4];
                        ROW15(acc, iv,   wp);
                        ROW15(acc, ga.x, wp + 30);  ROW15(acc, ga.y, wp + 60);
                        ROW15(acc, ga.z, wp + 90);  ROW15(acc, ga.w, wp + 120);
                        ROW15(acc, gb.x, wp + 150); ROW15(acc, gb.y, wp + 180);
                        ROW15(acc, gb.z, wp + 210); ROW15(acc, gb.w, wp + 240);
                        ROW15(acc, gc.x, wp + 270); ROW15(acc, gc.y, wp + 300);
                        ROW15(acc, gc.z, wp + 330); ROW15(acc, gc.w, wp + 360);
                        ROW15(acc, gd.x, wp + 390); ROW15(acc, gd.y, wp + 420);
                        ROW15(acc, gd.z, wp + 450); ROW15(acc, gd.w, wp + 480);
                        ROW15(acc, ge.x, wp + 510); ROW15(acc, ge.y, wp + 540);
                        ROW15(acc, ge.z, wp + 570);
                    }
                }
            }
            const float posx = (float)(px - 16) * 0.0625f;
            const float posy = (float)(py - 16) * 0.0625f;
            ROW15(acc, posx, W1 + 180 * 30 + qoff);
            ROW15(acc, posy, W1 + 181 * 30 + qoff);
        }
#pragma unroll
        for (int o = 0; o < 15; o++) a1[o] = fmaxf(acc[o], 0.0f);
        if (active) {
#pragma unroll
            for (int o = 0; o < 15; o++) s_h[cell * HSTRIDE + qoff + o] = a1[o];
        }
    }
    __syncthreads();                                  // B2: a1 visible

    // ---------------- layer 2: 30 -> 30 (this thread: 15 @ qoff) -----------
    float h2[15];
    {
        float acc[15];
#pragma unroll
        for (int o = 0; o < 15; o++) acc[o] = b2[qoff + o];
        if (active) {
            if (h == 0) {
#pragma unroll
                for (int k = 0; k < 15; k++)
                    ROW15(acc, a1[k], W2 + k * 30);
#pragma clang loop unroll(disable)
                for (int k = 15; k < 30; k++) {
                    const float x = s_h[cell * HSTRIDE + k];
                    ROW15(acc, x, W2 + k * 30);
                }
            } else {
#pragma clang loop unroll(disable)
                for (int k = 0; k < 15; k++) {
                    const float x = s_h[cell * HSTRIDE + k];
                    ROW15(acc, x, W2 + k * 30 + 15);
                }
#pragma unroll
                for (int k = 0; k < 15; k++)
                    ROW15(acc, a1[k], W2 + (k + 15) * 30 + 15);
            }
        }
#pragma unroll
        for (int o = 0; o < 15; o++) h2[o] = fmaxf(acc[o], 0.0f);
    }
    __syncthreads();                                  // B3: all a1 reads done
    if (active) {
#pragma unroll
        for (int o = 0; o < 15; o++) s_h[cell * HSTRIDE + qoff + o] = h2[o];
    }
    __syncthreads();                                  // B4: h2 visible

    // ---------------- layer 3: 30 -> 21 (h0: cols 0-11, h1: cols 12-20) ----
    if (active) {
        const size_t coff = (((size_t)b * NPIX + (i + 1)) * NPIX + (j + 1)) * CPAD;
        const int    lc   = ((r + 1) * NPIX + (j + 1)) * CPAD;
        if (h == 0) {
            float ov[12];
#pragma unroll
            for (int c = 0; c < 12; c++) ov[c] = b3[c];
#pragma unroll
            for (int k = 0; k < 15; k++)
                ROW12(ov, h2[k], W3 + k * 21);
#pragma clang loop unroll(disable)
            for (int k = 15; k < 30; k++) {
                const float x = s_h[cell * HSTRIDE + k];
                ROW12(ov, x, W3 + k * 21);
            }
            if (MODE == 2) {
                float* __restrict__ g = guesses_out + (size_t)gcell * OUTD;
#pragma unroll
                for (int c = 0; c < 12; c++) g[c] = ov[c];
            } else {
                float4* __restrict__ ns4 = (float4*)(state_new + coff);
                if (MODE == 0) {
                    ns4[0] = make_float4(ov[0], ov[1], ov[2],  ov[3]);
                    ns4[1] = make_float4(ov[4], ov[5], ov[6],  ov[7]);
                    ns4[2] = make_float4(ov[8], ov[9], ov[10], ov[11]);
                } else {
                    const float4* __restrict__ cs4 = (const float4*)&s_state[lc];
                    const float4 c0 = cs4[0], c1 = cs4[1], c2 = cs4[2];
                    ns4[0] = make_float4(c0.x + ov[0], c0.y + ov[1],
                                         c0.z + ov[2], c0.w + ov[3]);
                    ns4[1] = make_float4(c1.x + ov[4], c1.y + ov[5],
                                         c1.z + ov[6], c1.w + ov[7]);
                    ns4[2] = make_float4(c2.x + ov[8], c2.y + ov[9],
                                         c2.z + ov[10], c2.w + ov[11]);
                }
            }
        } else {
            float ov[9];                              // global cols 12..20
#pragma unroll
            for (int c = 0; c < 9; c++) ov[c] = b3[12 + c];
#pragma clang loop unroll(disable)
            for (int k = 0; k < 15; k++) {
                const float x = s_h[cell * HSTRIDE + k];
                ROW9(ov, x, W3 + k * 21 + 12);
            }
#pragma unroll
            for (int k = 0; k < 15; k++)
                ROW9(ov, h2[k], W3 + (k + 15) * 21 + 12);
            if (MODE == 2) {
                float* __restrict__ g = guesses_out + (size_t)gcell * OUTD;
#pragma unroll
                for (int c = 0; c < 9; c++) g[12 + c] = ov[c];
                const float4 c4 = *(const float4*)&s_state[lc + 16]; // ch16..19
                float* __restrict__ cs = class_out + (size_t)gcell * 3;
                cs[0] = c4.x + ov[4];   // global ov16
                cs[1] = c4.y + ov[5];   // global ov17
                cs[2] = c4.z + ov[6];   // global ov18
            } else {
                float4* __restrict__ ns4 = (float4*)(state_new + coff);
                if (MODE == 0) {
                    ns4[3] = make_float4(ov[0], ov[1], ov[2], ov[3]);
                    ns4[4] = make_float4(ov[4], ov[5], ov[6], 0.0f);
                } else {
                    const float4 c3 = *(const float4*)&s_state[lc + 12];
                    const float4 c4 = *(const float4*)&s_state[lc + 16];
                    ns4[3] = make_float4(c3.x + ov[0], c3.y + ov[1],
                                         c3.z + ov[2], c3.w + ov[3]);
                    ns4[4] = make_float4(c4.x + ov[4], c4.y + ov[5],
                                         c4.z + ov[6], 0.0f);
                }
                int dxm = (ov[7] > THRESHV) ? 1 : ((ov[7] < -THRESHV) ? -1 : 0);
                int dym = (ov[8] > THRESHV) ? 1 : ((ov[8] < -THRESHV) ? -1 : 0);
                px += dxm; py += dym;
                px = (px < 0) ? 0 : ((px > NNEO - 1) ? NNEO - 1 : px);
                py = (py < 0) ? 0 : ((py > NNEO - 1) ? NNEO - 1 : py);
                perc[2 * gcell + 0] = px;
                perc[2 * gcell + 1] = py;
            }
        }
    }
}

extern "C" void kernel_launch(void* const* d_in, const int* in_sizes, int n_in,
                              void* d_out, int out_size, void* d_ws, size_t ws_size,
                              hipStream_t stream) {
    const float* img = (const float*)d_in[0];
    const float* W1  = (const float*)d_in[1];
    const float* b1  = (const float*)d_in[2];
    const float* W2  = (const float*)d_in[3];
    const float* b2  = (const float*)d_in[4];
    const float* W3  = (const float*)d_in[5];
    const float* b3  = (const float*)d_in[6];

    float* out = (float*)d_out;
    float* class_out   = out;                 // 345,600 floats
    float* guesses_out = out + CLASS_ELEMS;   // 2,419,200 floats

    float* stateA = (float*)d_ws;
    float* stateB = stateA + STATE_ELEMS_PAD;
    int*   perc   = (int*)(stateB + STATE_ELEMS_PAD);

    {
        const int total = B_ * 124 * CPAD;
        nca_init<<<(total + 255) / 256, 256, 0, stream>>>(stateA, stateB);
    }

    const dim3 grid(4, B_);                   // 512 blocks = 2/CU exactly
    // t = 0: state==0, perc = identity; writes stateB + perc
    nca_step<0><<<grid, 512, 0, stream>>>(img, W1, b1, W2, b2, W3, b3,
                                          stateA, stateB, perc,
                                          guesses_out, class_out);
    // t = 1..8: ping-pong
    for (int t = 1; t < ITERS - 1; t++) {
        const float* so = (t & 1) ? stateB : stateA;
        float*       sn = (t & 1) ? stateA : stateB;
        nca_step<1><<<grid, 512, 0, stream>>>(img, W1, b1, W2, b2, W3, b3,
                                              so, sn, perc,
                                              guesses_out, class_out);
    }
    // t = 9 (odd): reads stateB, emits outputs only
    nca_step<2><<<grid, 512, 0, stream>>>(img, W1, b1, W2, b2, W3, b3,
                                          stateB, stateA, perc,
                                          guesses_out, class_out);
}

// Round 13
// 336.580 us; speedup vs baseline: 1.8324x; 1.0347x over previous
//
#include <hip/hip_runtime.h>

// Problem constants (from reference)
#define B_      128
#define NPIX    32      // N = M = 32
#define NNEO    30      // N-2
#define CPAD    20      // padded channel stride (16B-aligned pixel blocks)
#define OUTD    21      // OUT_DIM
#define ITERS   10
#define THRESHV 0.0007f
#define HSTRIDE 31      // s_h cell stride: gcd(31,32)=1 -> conflict-free

#define STATE_ELEMS_PAD (B_ * NPIX * NPIX * CPAD)  // 2,621,440 floats per buffer
#define NCELLS      (B_ * NNEO * NNEO)             // 115,200
#define CLASS_ELEMS (NCELLS * 3)                   // 345,600

// ---------------------------------------------------------------------------
// R23 = R14 VERBATIM (the session's proven best: 336.4us, steps 43.5-44.6us).
// R22's micro-opts (global_load_lds staging, perc hoist) measured SLOWER
// (steps 46-50us) — reverted. Structure-space summary after 12 rounds:
//   half-split + interleaved-CPAD LDS staging (this) ...... 336  <- best
//   quarter-split interleaved (R0 baseline) .............. 347
//   planar layouts (R16/R17) ............................. 383-395
//   one-thread-per-cell (R11/R13/R15) .................... 479-780 (TLP cap)
//   persistent LDS-resident (R20/R21) .................... 419/617 (occupancy
//                                                / per-XCD L2 coherence cost)
// Remaining gap to the ~13us/step VALU floor is the lgkmcnt coupling of
// s_load weights with ds_read activations + barrier lockstep; all source-
// level attempts to decouple (R15 vmcnt-fv, R17 imm-offset planar) regressed.
// MODE: 0 = first step (state==0, perc=identity), 1 = mid, 2 = last.
// ---------------------------------------------------------------------------

__global__ void nca_init(float* __restrict__ stateA, float* __restrict__ stateB) {
    int idx = blockIdx.x * blockDim.x + threadIdx.x;
    const int total = B_ * 124 * CPAD;
    if (idx >= total) return;
    int c  = idx % CPAD;
    int t2 = idx / CPAD;
    int cellp = t2 % 124;
    int b    = t2 / 124;
    int i, j;
    if (cellp < 32)      { i = 0;  j = cellp; }
    else if (cellp < 64) { i = 31; j = cellp - 32; }
    else { int k = cellp - 64; i = 1 + (k >> 1); j = (k & 1) ? 31 : 0; }
    size_t off = (((size_t)b * NPIX + i) * NPIX + j) * CPAD + c;
    stateA[off] = 0.0f;
    stateB[off] = 0.0f;
}

#define ROW15(A, x, wrp) do { const float xx_ = (x); \
    const float* __restrict__ w_ = (wrp); \
    _Pragma("unroll") for (int o_ = 0; o_ < 15; o_++) (A)[o_] += xx_ * w_[o_]; \
} while (0)

#define ROW12(A, x, wrp) do { const float xx_ = (x); \
    const float* __restrict__ w_ = (wrp); \
    _Pragma("unroll") for (int o_ = 0; o_ < 12; o_++) (A)[o_] += xx_ * w_[o_]; \
} while (0)

#define ROW9(A, x, wrp) do { const float xx_ = (x); \
    const float* __restrict__ w_ = (wrp); \
    _Pragma("unroll") for (int o_ = 0; o_ < 9; o_++) (A)[o_] += xx_ * w_[o_]; \
} while (0)

template<int MODE>
__global__ __launch_bounds__(512, 4)
void nca_step(const float* __restrict__ img,
              const float* __restrict__ W1, const float* __restrict__ b1,
              const float* __restrict__ W2, const float* __restrict__ b2,
              const float* __restrict__ W3, const float* __restrict__ b3,
              const float* __restrict__ state_old, float* __restrict__ state_new,
              int* perc, float* __restrict__ guesses_out,
              float* __restrict__ class_out)
{
    __shared__ float s_state[10 * NPIX * CPAD];   // 25.6 KB (nr+2 <= 10 rows)
    __shared__ float s_img[NPIX * NPIX];          // 4 KB
    __shared__ float s_h[256 * HSTRIDE];          // 31.7 KB   (total 61.3 KB)

    const int b   = blockIdx.y;
    const int rg  = blockIdx.x;                   // 4 groups: rows {8,8,8,6}
    const int i0  = rg * 8;
    const int nr  = (rg == 3) ? 6 : 8;
    const int tid = threadIdx.x;
    const int h   = __builtin_amdgcn_readfirstlane(tid >> 8);  // wave-uniform half
    const int cell = tid & 255;
    const int qoff = h * 15;

    // ---- stage state rows [i0, i0+nr+2) and the image ----------------------
    if (MODE != 0) {
        const int n4 = (nr + 2) * (NPIX * CPAD / 4);   // 1600 or 1280 float4
        const float4* __restrict__ gstate4 =
            (const float4*)(state_old + ((size_t)b * NPIX + i0) * (NPIX * CPAD));
        float4* s4 = (float4*)s_state;
        for (int t = tid; t < n4; t += 512) s4[t] = gstate4[t];
    }
    if (tid < 256)
        ((float4*)s_img)[tid] = ((const float4*)(img + (size_t)b * NPIX * NPIX))[tid];
    __syncthreads();                                  // B1

    const int cells = nr * NNEO;
    const bool active = cell < cells;

    int r = 0, j = 0, i = 0, gcell = 0, px = 0, py = 0;
    if (active) {
        r = cell / NNEO;
        j = cell - r * NNEO;
        i = i0 + r;
        gcell = (b * NNEO + i) * NNEO + j;
        if (MODE == 0) { px = i; py = j; }
        else           { px = perc[2 * gcell]; py = perc[2 * gcell + 1]; }
    }

    // ---------------- layer 1: 182 -> 30 (this thread: 15 @ qoff) ----------
    float a1[15];
    {
        float acc[15];
#pragma unroll
        for (int o = 0; o < 15; o++) acc[o] = b1[qoff + o];
        if (active) {
            if (MODE == 0) {
#pragma clang loop unroll(disable)
                for (int pr = 0; pr < 3; pr++) {
#pragma clang loop unroll(disable)
                    for (int pc = 0; pc < 3; pc++) {
                        const float iv = s_img[(px + pr) * NPIX + (py + pc)];
                        ROW15(acc, iv, W1 + (pr * 3 + pc) * 600 + qoff);
                    }
                }
            } else {
#pragma clang loop unroll(disable)
                for (int pr = 0; pr < 3; pr++) {
#pragma clang loop unroll(disable)
                    for (int pc = 0; pc < 3; pc++) {
                        const float iv = s_img[(px + pr) * NPIX + (py + pc)];
                        const float* __restrict__ wp = W1 + (pr * 3 + pc) * 600 + qoff;
                        const float4* __restrict__ sp =
                            (const float4*)&s_state[((r + pr) * NPIX + (j + pc)) * CPAD];
                        const float4 ga = sp[0], gb = sp[1], gc = sp[2],
                                     gd = sp[3], ge = sp[4];
                        ROW15(acc, iv,   wp);
                        ROW15(acc, ga.x, wp + 30);  ROW15(acc, ga.y, wp + 60);
                        ROW15(acc, ga.z, wp + 90);  ROW15(acc, ga.w, wp + 120);
                        ROW15(acc, gb.x, wp + 150); ROW15(acc, gb.y, wp + 180);
                        ROW15(acc, gb.z, wp + 210); ROW15(acc, gb.w, wp + 240);
                        ROW15(acc, gc.x, wp + 270); ROW15(acc, gc.y, wp + 300);
                        ROW15(acc, gc.z, wp + 330); ROW15(acc, gc.w, wp + 360);
                        ROW15(acc, gd.x, wp + 390); ROW15(acc, gd.y, wp + 420);
                        ROW15(acc, gd.z, wp + 450); ROW15(acc, gd.w, wp + 480);
                        ROW15(acc, ge.x, wp + 510); ROW15(acc, ge.y, wp + 540);
                        ROW15(acc, ge.z, wp + 570);
                    }
                }
            }
            const float posx = (float)(px - 16) * 0.0625f;
            const float posy = (float)(py - 16) * 0.0625f;
            ROW15(acc, posx, W1 + 180 * 30 + qoff);
            ROW15(acc, posy, W1 + 181 * 30 + qoff);
        }
#pragma unroll
        for (int o = 0; o < 15; o++) a1[o] = fmaxf(acc[o], 0.0f);
        if (active) {
#pragma unroll
            for (int o = 0; o < 15; o++) s_h[cell * HSTRIDE + qoff + o] = a1[o];
        }
    }
    __syncthreads();                                  // B2: a1 visible

    // ---------------- layer 2: 30 -> 30 (this thread: 15 @ qoff) -----------
    float h2[15];
    {
        float acc[15];
#pragma unroll
        for (int o = 0; o < 15; o++) acc[o] = b2[qoff + o];
        if (active) {
            if (h == 0) {
#pragma unroll
                for (int k = 0; k < 15; k++)
                    ROW15(acc, a1[k], W2 + k * 30);
#pragma clang loop unroll(disable)
                for (int k = 15; k < 30; k++) {
                    const float x = s_h[cell * HSTRIDE + k];
                    ROW15(acc, x, W2 + k * 30);
                }
            } else {
#pragma clang loop unroll(disable)
                for (int k = 0; k < 15; k++) {
                    const float x = s_h[cell * HSTRIDE + k];
                    ROW15(acc, x, W2 + k * 30 + 15);
                }
#pragma unroll
                for (int k = 0; k < 15; k++)
                    ROW15(acc, a1[k], W2 + (k + 15) * 30 + 15);
            }
        }
#pragma unroll
        for (int o = 0; o < 15; o++) h2[o] = fmaxf(acc[o], 0.0f);
    }
    __syncthreads();                                  // B3: all a1 reads done
    if (active) {
#pragma unroll
        for (int o = 0; o < 15; o++) s_h[cell * HSTRIDE + qoff + o] = h2[o];
    }
    __syncthreads();                                  // B4: h2 visible

    // ---------------- layer 3: 30 -> 21 (h0: cols 0-11, h1: cols 12-20) ----
    if (active) {
        const size_t coff = (((size_t)b * NPIX + (i + 1)) * NPIX + (j + 1)) * CPAD;
        const int    lc   = ((r + 1) * NPIX + (j + 1)) * CPAD;
        if (h == 0) {
            float ov[12];
#pragma unroll
            for (int c = 0; c < 12; c++) ov[c] = b3[c];
#pragma unroll
            for (int k = 0; k < 15; k++)
                ROW12(ov, h2[k], W3 + k * 21);
#pragma clang loop unroll(disable)
            for (int k = 15; k < 30; k++) {
                const float x = s_h[cell * HSTRIDE + k];
                ROW12(ov, x, W3 + k * 21);
            }
            if (MODE == 2) {
                float* __restrict__ g = guesses_out + (size_t)gcell * OUTD;
#pragma unroll
                for (int c = 0; c < 12; c++) g[c] = ov[c];
            } else {
                float4* __restrict__ ns4 = (float4*)(state_new + coff);
                if (MODE == 0) {
                    ns4[0] = make_float4(ov[0], ov[1], ov[2],  ov[3]);
                    ns4[1] = make_float4(ov[4], ov[5], ov[6],  ov[7]);
                    ns4[2] = make_float4(ov[8], ov[9], ov[10], ov[11]);
                } else {
                    const float4* __restrict__ cs4 = (const float4*)&s_state[lc];
                    const float4 c0 = cs4[0], c1 = cs4[1], c2 = cs4[2];
                    ns4[0] = make_float4(c0.x + ov[0], c0.y + ov[1],
                                         c0.z + ov[2], c0.w + ov[3]);
                    ns4[1] = make_float4(c1.x + ov[4], c1.y + ov[5],
                                         c1.z + ov[6], c1.w + ov[7]);
                    ns4[2] = make_float4(c2.x + ov[8], c2.y + ov[9],
                                         c2.z + ov[10], c2.w + ov[11]);
                }
            }
        } else {
            float ov[9];                              // global cols 12..20
#pragma unroll
            for (int c = 0; c < 9; c++) ov[c] = b3[12 + c];
#pragma clang loop unroll(disable)
            for (int k = 0; k < 15; k++) {
                const float x = s_h[cell * HSTRIDE + k];
                ROW9(ov, x, W3 + k * 21 + 12);
            }
#pragma unroll
            for (int k = 0; k < 15; k++)
                ROW9(ov, h2[k], W3 + (k + 15) * 21 + 12);
            if (MODE == 2) {
                float* __restrict__ g = guesses_out + (size_t)gcell * OUTD;
#pragma unroll
                for (int c = 0; c < 9; c++) g[12 + c] = ov[c];
                const float4 c4 = *(const float4*)&s_state[lc + 16]; // ch16..19
                float* __restrict__ cs = class_out + (size_t)gcell * 3;
                cs[0] = c4.x + ov[4];   // global ov16
                cs[1] = c4.y + ov[5];   // global ov17
                cs[2] = c4.z + ov[6];   // global ov18
            } else {
                float4* __restrict__ ns4 = (float4*)(state_new + coff);
                if (MODE == 0) {
                    ns4[3] = make_float4(ov[0], ov[1], ov[2], ov[3]);
                    ns4[4] = make_float4(ov[4], ov[5], ov[6], 0.0f);
                } else {
                    const float4 c3 = *(const float4*)&s_state[lc + 12];
                    const float4 c4 = *(const float4*)&s_state[lc + 16];
                    ns4[3] = make_float4(c3.x + ov[0], c3.y + ov[1],
                                         c3.z + ov[2], c3.w + ov[3]);
                    ns4[4] = make_float4(c4.x + ov[4], c4.y + ov[5],
                                         c4.z + ov[6], 0.0f);
                }
                int dxm = (ov[7] > THRESHV) ? 1 : ((ov[7] < -THRESHV) ? -1 : 0);
                int dym = (ov[8] > THRESHV) ? 1 : ((ov[8] < -THRESHV) ? -1 : 0);
                px += dxm; py += dym;
                px = (px < 0) ? 0 : ((px > NNEO - 1) ? NNEO - 1 : px);
                py = (py < 0) ? 0 : ((py > NNEO - 1) ? NNEO - 1 : py);
                perc[2 * gcell + 0] = px;
                perc[2 * gcell + 1] = py;
            }
        }
    }
}

extern "C" void kernel_launch(void* const* d_in, const int* in_sizes, int n_in,
                              void* d_out, int out_size, void* d_ws, size_t ws_size,
                              hipStream_t stream) {
    const float* img = (const float*)d_in[0];
    const float* W1  = (const float*)d_in[1];
    const float* b1  = (const float*)d_in[2];
    const float* W2  = (const float*)d_in[3];
    const float* b2  = (const float*)d_in[4];
    const float* W3  = (const float*)d_in[5];
    const float* b3  = (const float*)d_in[6];

    float* out = (float*)d_out;
    float* class_out   = out;                 // 345,600 floats
    float* guesses_out = out + CLASS_ELEMS;   // 2,419,200 floats

    float* stateA = (float*)d_ws;
    float* stateB = stateA + STATE_ELEMS_PAD;
    int*   perc   = (int*)(stateB + STATE_ELEMS_PAD);

    {
        const int total = B_ * 124 * CPAD;
        nca_init<<<(total + 255) / 256, 256, 0, stream>>>(stateA, stateB);
    }

    const dim3 grid(4, B_);                   // 512 blocks = 2/CU exactly
    // t = 0: state==0, perc = identity; writes stateB + perc
    nca_step<0><<<grid, 512, 0, stream>>>(img, W1, b1, W2, b2, W3, b3,
                                          stateA, stateB, perc,
                                          guesses_out, class_out);
    // t = 1..8: ping-pong
    for (int t = 1; t < ITERS - 1; t++) {
        const float* so = (t & 1) ? stateB : stateA;
        float*       sn = (t & 1) ? stateA : stateB;
        nca_step<1><<<grid, 512, 0, stream>>>(img, W1, b1, W2, b2, W3, b3,
                                              so, sn, perc,
                                              guesses_out, class_out);
    }
    // t = 9 (odd): reads stateB, emits outputs only
    nca_step<2><<<grid, 512, 0, stream>>>(img, W1, b1, W2, b2, W3, b3,
                                          stateB, stateA, perc,
                                          guesses_out, class_out);
}